// Round 1
// 188.595 us; speedup vs baseline: 1.0130x; 1.0130x over previous
//
#include <hip/hip_runtime.h>

// MFVIConstituency: B=16, S=128, MAX_ITER=3.
// q_new[b,i,j] = s_span[b,i,j] + sum_k sigmoid(q[b,i,k]) * sp[b,i,j,k]
// sp[b,i,j,k]  = s_pair[b,i,j,k] * ( mask[b,i,j] & (k!=min(i,j)) & (k!=max(i,j))
//                                     & (mask[b,j,k]|mask[b,k,j]) )
//
// Round-4: DPP reduction package.
//  - part[]-LDS reduction + serial wave-0 reducer + 2 barriers/iter replaced by
//    5 DPP adds (row_shr 1/2/4/8 + row_bcast15) per slot; lanes 31/63 hold the
//    two half-wave row sums. 1 barrier/iter, LDS 20.6 KB -> 3.8 KB.
//  - prow double-buffered (both buffers init'd -> inactive rows stay constant).
//  - active-row indices cached in registers (js_p byte-packed), not re-read
//    from LDS each iteration.
//  - nontemporal loads for the stream-once s_pair.
//  - pack_masks: 64 blocks (phase-2 split 4x/batch); miw dropped -- main
//    ballots its own 512 B mask row.

#define S 128
#define MB_STRIDE 132     // mask byte tile: transposed byte reads conflict-free

typedef float f4 __attribute__((ext_vector_type(4)));

static __device__ __forceinline__ float fsig(float x) {
    return __builtin_amdgcn_rcpf(1.0f + __expf(-x));
}

// y = dpp_mov(x) with zero-fill; caller does acc += y.
template<int CTRL, int RM>
static __device__ __forceinline__ float dpp_red(float x) {
    return __int_as_float(__builtin_amdgcn_update_dpp(
        0, __float_as_int(x), CTRL, RM, 0xF, false));
}

// ---------------- pre-pack: span bitmasks per (batch, j-quarter) ----------------
__global__ __launch_bounds__(256, 2) void pack_masks(
    const int* __restrict__ mask, unsigned* __restrict__ spanw)
{
    __shared__ __align__(16) unsigned char mb[S * MB_STRIDE];   // 16896 B
    const int t    = threadIdx.x;
    const int b    = blockIdx.x >> 2;
    const int part = blockIdx.x & 3;
    const int* mrow = mask + (long long)b * (S * S);
    #pragma unroll
    for (int s2 = 0; s2 < 16; ++s2) {
        int f4i = t + 256 * s2;           // int4 index 0..4095
        int j   = f4i >> 5;
        int k0  = (f4i & 31) * 4;
        int4 vv = *(const int4*)(mrow + f4i * 4);
        unsigned packed = (vv.x ? 1u : 0u)
                        | ((vv.y ? 1u : 0u) << 8)
                        | ((vv.z ? 1u : 0u) << 16)
                        | ((vv.w ? 1u : 0u) << 24);
        *(unsigned*)(mb + j * MB_STRIDE + k0) = packed;
    }
    __syncthreads();
    if (t < 128) {                         // 128 tasks = (32 j's of this part) x 4 words
        int j = part * 32 + (t >> 2), w = t & 3;
        unsigned sbits = 0;
        #pragma unroll
        for (int c = 0; c < 32; ++c) {
            int k = w * 32 + c;
            unsigned mjk = mb[j * MB_STRIDE + k];
            unsigned mkj = mb[k * MB_STRIDE + j];
            sbits |= ((mjk | mkj) ? 1u : 0u) << c;
        }
        spanw[(b * S + j) * 4 + w] = sbits;   // bit k: mask[b,j,k]|mask[b,k,j]
    }
}

// ---------------- main: one block per (b,i), active rows only ----------------
__global__ __launch_bounds__(256, 4) void mfvi_main(
    const float* __restrict__ s_span,
    const float* __restrict__ s_pair,
    const int* __restrict__ mask,
    const unsigned* __restrict__ spanw,
    float* __restrict__ out)
{
    __shared__ __align__(16) unsigned sw_l[S * 4];   // 2048 B
    __shared__ __align__(16) float prow[2][S];       // sigmoid(q), ping-pong
    __shared__ float qsv[S];                         // s_span row
    __shared__ unsigned char act[S];                 // compact active-j list
    __shared__ int nact_s;

    const int t  = threadIdx.x;
    const int bi = blockIdx.x;        // b*128 + i
    const int i  = bi & (S - 1);
    const int b  = bi >> 7;
    const int row0 = t >> 5;          // 0..7
    const int c4   = (t & 31) * 4;    // k base 0..124
    const float* tile = s_pair + (long long)bi * (S * S);
    const int*   mrow = mask + (long long)bi * S;    // mask[b,i,:]

    // ---- init: span words, s_span, initial p (both buffers), compaction ----
    if (t < S) *(uint4*)&sw_l[t * 4] = *(const uint4*)&spanw[(b * S + t) * 4];
    if (t < S) {
        float sv = s_span[(long long)bi * S + t];
        qsv[t] = sv;
        float pf = fsig(sv);
        prow[0][t] = pf;
        prow[1][t] = pf;              // inactive rows keep this in BOTH buffers
        if (mrow[t] == 0)             // inactive row: q stays s_span forever
            out[(long long)bi * S + t] = pf;
    }
    if (t < 64) {                     // wave 0 compacts j=0..127 in two ballots
        bool a0 = mrow[t] != 0;
        unsigned long long b0 = __ballot(a0);
        int p0 = __popcll(b0 & ((1ull << t) - 1ull));
        if (a0) act[p0] = (unsigned char)t;
        int n0 = __popcll(b0);
        bool a1 = mrow[t + 64] != 0;
        unsigned long long b1 = __ballot(a1);
        int p1 = n0 + __popcll(b1 & ((1ull << t) - 1ull));
        if (a1) act[p1] = (unsigned char)(t + 64);
        if (t == 0) nact_s = n0 + __popcll(b1);
    }
    __syncthreads();
    const int nact = nact_s;

    // ---- load + mask only active rows (compact idx = row0 + 8s) ----
    f4 v[16];
    unsigned js_p[4] = {0u, 0u, 0u, 0u};   // 16 byte-packed active-row indices
    #pragma unroll
    for (int s = 0; s < 16; ++s) {
        const int idx = row0 + 8 * s;
        if (idx < nact) {
            const int j = act[idx];
            js_p[s >> 2] |= (unsigned)j << (8 * (s & 3));
            f4 t4 = __builtin_nontemporal_load((const f4*)(tile + j * S + c4));
            unsigned cw = sw_l[j * 4 + (c4 >> 5)];
            const int lo = i < j ? i : j, hi = i < j ? j : i;
            if ((lo >> 5) == (c4 >> 5)) cw &= ~(1u << (lo & 31));
            if ((hi >> 5) == (c4 >> 5)) cw &= ~(1u << (hi & 31));
            const unsigned cs = cw >> (c4 & 31);   // bits 0..3 = this thread's 4 k's
            const int m0 = ((int)(cs << 31)) >> 31;
            const int m1 = ((int)(cs << 30)) >> 31;
            const int m2 = ((int)(cs << 29)) >> 31;
            const int m3 = ((int)(cs << 28)) >> 31;
            t4.x = __int_as_float(__float_as_int(t4.x) & m0);
            t4.y = __int_as_float(__float_as_int(t4.y) & m1);
            t4.z = __int_as_float(__float_as_int(t4.z) & m2);
            t4.w = __int_as_float(__float_as_int(t4.w) & m3);
            v[s] = t4;
        }
    }

    // ---- 3 MFVI iterations, DPP half-wave reduction, 1 barrier/iter ----
    #pragma unroll
    for (int it = 0; it < 3; ++it) {
        const int cur = it & 1;
        f4 p = *(const f4*)&prow[cur][c4];   // ds_read_b128, 2-way bcast (free)
        #pragma unroll
        for (int s = 0; s < 16; ++s) {
            const int idx = row0 + 8 * s;
            if (idx < nact) {
                float acc = v[s].x * p.x + v[s].y * p.y
                          + v[s].z * p.z + v[s].w * p.w;
                // sum within each 32-lane half-wave; results at lanes 31 / 63
                acc += dpp_red<0x111, 0xF>(acc);   // row_shr:1
                acc += dpp_red<0x112, 0xF>(acc);   // row_shr:2
                acc += dpp_red<0x114, 0xF>(acc);   // row_shr:4
                acc += dpp_red<0x118, 0xF>(acc);   // row_shr:8
                acc += dpp_red<0x142, 0xA>(acc);   // row_bcast15 into rows 1,3
                if ((t & 31) == 31) {
                    const int j = (int)((js_p[s >> 2] >> (8 * (s & 3))) & 0xFFu);
                    const float q = qsv[j] + acc;
                    if (it < 2) prow[cur ^ 1][j] = fsig(q);
                    else        out[(long long)bi * S + j] = fsig(q);
                }
            }
        }
        if (it < 2) __syncthreads();
    }
}

extern "C" void kernel_launch(void* const* d_in, const int* in_sizes, int n_in,
                              void* d_out, int out_size, void* d_ws, size_t ws_size,
                              hipStream_t stream) {
    const float* s_span = (const float*)d_in[0];
    const float* s_pair = (const float*)d_in[1];
    const int*   mask   = (const int*)d_in[2];
    float*       out    = (float*)d_out;

    int num_rows = in_sizes[0] / S;        // B*S = 2048
    int B        = in_sizes[2] / (S * S);  // 16

    unsigned* ws_span = (unsigned*)d_ws;   // B*S*4 uints = 32 KB

    pack_masks<<<B * 4, 256, 0, stream>>>(mask, ws_span);
    mfvi_main<<<num_rows, 256, 0, stream>>>(s_span, s_pair, mask, ws_span, out);
}

// Round 2
// 187.226 us; speedup vs baseline: 1.0204x; 1.0073x over previous
//
#include <hip/hip_runtime.h>

// MFVIConstituency: B=16, S=128, MAX_ITER=3.
// q_new[b,i,j] = s_span[b,i,j] + sum_k sigmoid(q[b,i,k]) * sp[b,i,j,k]
// sp[b,i,j,k]  = s_pair[b,i,j,k] * ( mask[b,i,j] & (k!=min(i,j)) & (k!=max(i,j))
//                                     & (mask[b,j,k]|mask[b,k,j]) )
//
// Round-5: kill the exec-mask load serialization.
//  - The 16 s_pair row loads were each inside `if (idx < nact)` with a
//    non-provably-uniform predicate -> 16 saveexec regions, each load
//    waiting full HBM latency before the next issued (~1 load in flight
//    per wave). Now: loads are UNCONDITIONAL (dead slots clamp to act[0],
//    L1-served dup), zeroing folded into the span bitmask -> 16 loads
//    clustered per wave, kernel becomes genuinely HBM-bound.
//  - nact hoisted to SGPR via readfirstlane; iteration loop skips dead
//    slots with a scalar s_cbranch (no exec-mask cost, no VALU on dead).
//  - Epilogue: final iter writes prow[1] (inactive rows already correct
//    there), then one coalesced 512 B store; scattered 4 B stores gone.

#define S 128
#define MB_STRIDE 132     // mask byte tile: transposed byte reads conflict-free

typedef float f4 __attribute__((ext_vector_type(4)));

static __device__ __forceinline__ float fsig(float x) {
    return __builtin_amdgcn_rcpf(1.0f + __expf(-x));
}

// y = dpp_mov(x) with zero-fill; caller does acc += y.
template<int CTRL, int RM>
static __device__ __forceinline__ float dpp_red(float x) {
    return __int_as_float(__builtin_amdgcn_update_dpp(
        0, __float_as_int(x), CTRL, RM, 0xF, false));
}

// ---------------- pre-pack: span bitmasks per (batch, j-quarter) ----------------
__global__ __launch_bounds__(256, 2) void pack_masks(
    const int* __restrict__ mask, unsigned* __restrict__ spanw)
{
    __shared__ __align__(16) unsigned char mb[S * MB_STRIDE];   // 16896 B
    const int t    = threadIdx.x;
    const int b    = blockIdx.x >> 2;
    const int part = blockIdx.x & 3;
    const int* mrow = mask + (long long)b * (S * S);
    #pragma unroll
    for (int s2 = 0; s2 < 16; ++s2) {
        int f4i = t + 256 * s2;           // int4 index 0..4095
        int j   = f4i >> 5;
        int k0  = (f4i & 31) * 4;
        int4 vv = *(const int4*)(mrow + f4i * 4);
        unsigned packed = (vv.x ? 1u : 0u)
                        | ((vv.y ? 1u : 0u) << 8)
                        | ((vv.z ? 1u : 0u) << 16)
                        | ((vv.w ? 1u : 0u) << 24);
        *(unsigned*)(mb + j * MB_STRIDE + k0) = packed;
    }
    __syncthreads();
    if (t < 128) {                         // 128 tasks = (32 j's of this part) x 4 words
        int j = part * 32 + (t >> 2), w = t & 3;
        unsigned sbits = 0;
        #pragma unroll
        for (int c = 0; c < 32; ++c) {
            int k = w * 32 + c;
            unsigned mjk = mb[j * MB_STRIDE + k];
            unsigned mkj = mb[k * MB_STRIDE + j];
            sbits |= ((mjk | mkj) ? 1u : 0u) << c;
        }
        spanw[(b * S + j) * 4 + w] = sbits;   // bit k: mask[b,j,k]|mask[b,k,j]
    }
}

// ---------------- main: one block per (b,i), active rows only ----------------
__global__ __launch_bounds__(256, 4) void mfvi_main(
    const float* __restrict__ s_span,
    const float* __restrict__ s_pair,
    const int* __restrict__ mask,
    const unsigned* __restrict__ spanw,
    float* __restrict__ out)
{
    __shared__ __align__(16) unsigned sw_l[S * 4];   // 2048 B
    __shared__ __align__(16) float prow[2][S];       // sigmoid(q), ping-pong
    __shared__ float qsv[S];                         // s_span row
    __shared__ unsigned char act[S];                 // compact active-j list
    __shared__ int nact_s;

    const int t  = threadIdx.x;
    const int bi = blockIdx.x;        // b*128 + i
    const int i  = bi & (S - 1);
    const int b  = bi >> 7;
    const int row0 = t >> 5;          // 0..7
    const int c4   = (t & 31) * 4;    // k base 0..124
    const float* tile = s_pair + (long long)bi * (S * S);
    const int*   mrow = mask + (long long)bi * S;    // mask[b,i,:]

    // ---- init: span words, s_span, initial p (both buffers), compaction ----
    if (t < S) *(uint4*)&sw_l[t * 4] = *(const uint4*)&spanw[(b * S + t) * 4];
    if (t < S) {
        float sv = s_span[(long long)bi * S + t];
        qsv[t] = sv;
        float pf = fsig(sv);
        prow[0][t] = pf;
        prow[1][t] = pf;              // inactive rows keep this in BOTH buffers
    }
    if (t < 64) {                     // wave 0 compacts j=0..127 in two ballots
        bool a0 = mrow[t] != 0;
        unsigned long long b0 = __ballot(a0);
        int p0 = __popcll(b0 & ((1ull << t) - 1ull));
        if (a0) act[p0] = (unsigned char)t;
        int n0 = __popcll(b0);
        bool a1 = mrow[t + 64] != 0;
        unsigned long long b1 = __ballot(a1);
        int p1 = n0 + __popcll(b1 & ((1ull << t) - 1ull));
        if (a1) act[p1] = (unsigned char)(t + 64);
        if (t == 0) nact_s = n0 + __popcll(b1);
    }
    __syncthreads();
    const int nact = __builtin_amdgcn_readfirstlane(nact_s);   // SGPR -> uniform

    // ---- phase 1: 16 UNCONDITIONAL clustered loads (dead slots -> act[0]) ----
    f4 v[16];
    unsigned js_p[4] = {0u, 0u, 0u, 0u};   // 16 byte-packed row indices
    #pragma unroll
    for (int s = 0; s < 16; ++s) {
        const int idx = row0 + 8 * s;
        const int j = (idx < nact) ? (int)act[idx] : 0;   // cndmask, no branch
        js_p[s >> 2] |= (unsigned)j << (8 * (s & 3));
        v[s] = __builtin_nontemporal_load((const f4*)(tile + j * S + c4));
    }

    // ---- phase 2: apply span & (k!=lo,hi) mask; dead slots zeroed here ----
    #pragma unroll
    for (int s = 0; s < 16; ++s) {
        const int idx = row0 + 8 * s;
        const int j = (int)((js_p[s >> 2] >> (8 * (s & 3))) & 0xFFu);
        unsigned cw = sw_l[j * 4 + (c4 >> 5)];
        const int lo = i < j ? i : j, hi = i < j ? j : i;
        if ((lo >> 5) == (c4 >> 5)) cw &= ~(1u << (lo & 31));
        if ((hi >> 5) == (c4 >> 5)) cw &= ~(1u << (hi & 31));
        unsigned cs = cw >> (c4 & 31);     // bits 0..3 = this thread's 4 k's
        if (idx >= nact) cs = 0u;          // dead slot -> v[s] = 0
        const int m0 = ((int)(cs << 31)) >> 31;
        const int m1 = ((int)(cs << 30)) >> 31;
        const int m2 = ((int)(cs << 29)) >> 31;
        const int m3 = ((int)(cs << 28)) >> 31;
        v[s].x = __int_as_float(__float_as_int(v[s].x) & m0);
        v[s].y = __int_as_float(__float_as_int(v[s].y) & m1);
        v[s].z = __int_as_float(__float_as_int(v[s].z) & m2);
        v[s].w = __int_as_float(__float_as_int(v[s].w) & m3);
    }

    // ---- 3 MFVI iterations; scalar-uniform skip of fully-dead slots ----
    #pragma unroll
    for (int it = 0; it < 3; ++it) {
        const int cur = it & 1;
        f4 p = *(const f4*)&prow[cur][c4];   // ds_read_b128, 2-way bcast (free)
        #pragma unroll
        for (int s = 0; s < 16; ++s) {
            if (8 * s < nact) {              // SGPR compare -> s_cbranch, uniform
                const int idx = row0 + 8 * s;
                float acc = v[s].x * p.x + v[s].y * p.y
                          + v[s].z * p.z + v[s].w * p.w;
                // sum within each 32-lane half-wave; results at lanes 31 / 63
                acc += dpp_red<0x111, 0xF>(acc);   // row_shr:1
                acc += dpp_red<0x112, 0xF>(acc);   // row_shr:2
                acc += dpp_red<0x114, 0xF>(acc);   // row_shr:4
                acc += dpp_red<0x118, 0xF>(acc);   // row_shr:8
                acc += dpp_red<0x142, 0xA>(acc);   // row_bcast15 into rows 1,3
                if (((t & 31) == 31) && idx < nact) {
                    const int j = (int)((js_p[s >> 2] >> (8 * (s & 3))) & 0xFFu);
                    prow[cur ^ 1][j] = fsig(qsv[j] + acc);  // it=2 lands in prow[1]
                }
            }
        }
        __syncthreads();
    }

    // ---- coalesced epilogue: prow[1] holds final sigmoid for ALL rows ----
    if (t < S) out[(long long)bi * S + t] = prow[1][t];
}

extern "C" void kernel_launch(void* const* d_in, const int* in_sizes, int n_in,
                              void* d_out, int out_size, void* d_ws, size_t ws_size,
                              hipStream_t stream) {
    const float* s_span = (const float*)d_in[0];
    const float* s_pair = (const float*)d_in[1];
    const int*   mask   = (const int*)d_in[2];
    float*       out    = (float*)d_out;

    int num_rows = in_sizes[0] / S;        // B*S = 2048
    int B        = in_sizes[2] / (S * S);  // 16

    unsigned* ws_span = (unsigned*)d_ws;   // B*S*4 uints = 32 KB

    pack_masks<<<B * 4, 256, 0, stream>>>(mask, ws_span);
    mfvi_main<<<num_rows, 256, 0, stream>>>(s_span, s_pair, mask, ws_span, out);
}